// Round 10
// baseline (167.666 us; speedup 1.0000x reference)
//
#include <hip/hip_runtime.h>
#include <hip/hip_bf16.h>

typedef __bf16 bf16;
typedef __bf16 bf16x8 __attribute__((ext_vector_type(8)));
typedef __bf16 bf16x4 __attribute__((ext_vector_type(4)));
typedef float f32x4 __attribute__((ext_vector_type(4)));
typedef float f32x16 __attribute__((ext_vector_type(16)));
typedef unsigned int u32x4 __attribute__((ext_vector_type(4)));

#define MFMA16(a, b, c) __builtin_amdgcn_mfma_f32_16x16x32_bf16((a), (b), (c), 0, 0, 0)
#define MFMA32(a, b, c) __builtin_amdgcn_mfma_f32_32x32x16_bf16((a), (b), (c), 0, 0, 0)

constexpr int LQ = 2048, LK = 4096, E = 512, H = 8, DH = 64;
// q pre-scale: 1/sqrt(DH) * log2(e) folded into q-projection epilogue
#define QSCALE 0.1803368801111137f

#if __has_builtin(__builtin_amdgcn_exp2f)
#define EXP2(x) __builtin_amdgcn_exp2f(x)
#else
#define EXP2(x) __expf(0.6931471805599453f * (x))
#endif

__device__ __forceinline__ bf16x8 ld8(const bf16* p) { return *(const bf16x8*)p; }

// ------------- fp32 -> bf16 conversion of the 4 weight matrices ------------
__global__ __launch_bounds__(256) void cvt4_kernel(
    const float* __restrict__ w0, const float* __restrict__ w1,
    const float* __restrict__ w2, const float* __restrict__ w3,
    bf16* __restrict__ dst) {
  const float* srcs[4] = {w0, w1, w2, w3};
  const float* src = srcs[blockIdx.y];
  bf16* d = dst + (size_t)blockIdx.y * 262144;
  int i = (blockIdx.x * 256 + threadIdx.x) * 4;
  f32x4 v = *(const f32x4*)(src + i);
  bf16x4 o;
  for (int j = 0; j < 4; ++j) o[j] = (bf16)v[j];
  *(bf16x4*)(d + i) = o;
}

// ------------- q/k/v projection: r6 form (BK=64 dbuf, 72KB LDS) -----------
// K and V are written FRAGMENT-MAJOR for the attn kernel's 32x32 MFMAs:
//  Kf[bh][t32][j=st*2+hi][l31][e]  (elem = K[kk=t32*32+l31][d=j*8+e])
//  Vf[bh][t32][dt][s][hi][l31][e]  (elem = V[kk=t32*32+s*16+hi*8+e][d=dt*32+l31])
__global__ __launch_bounds__(256) void proj_gemm_kernel(
    const float* __restrict__ query, const float* __restrict__ kv,
    const bf16* __restrict__ Wall,
    const float* __restrict__ bq, const float* __restrict__ bk,
    const float* __restrict__ bv,
    bf16* __restrict__ qproj, bf16* __restrict__ kproj, bf16* __restrict__ vt) {
  __shared__ bf16 smA[2][128][72];
  __shared__ bf16 smB[2][128][72];
  const int tid = threadIdx.x;
  const int lane = tid & 63, wave = tid >> 6;
  const int lrow = lane & 15, quad = lane >> 4;
  const int wm = wave & 1, wn = wave >> 1;

  int x = blockIdx.x, z, mt;
  if (x < 32) { z = 0; mt = x; }
  else if (x < 96) { z = 1; mt = x - 32; }
  else { z = 2; mt = x - 96; }
  const float* A = ((z == 0) ? query : kv) + (size_t)mt * 128 * E;
  const bf16* W = Wall + (size_t)z * 262144;
  const float* bias = (z == 0) ? bq : (z == 1) ? bk : bv;
  const int n0 = blockIdx.y * 128;

  const int arow = tid >> 4, acol = tid & 15;
  const int brow = tid >> 3, bcol = tid & 7;

  f32x4 pa[8];
  bf16x8 pb[4];
#define LOAD_T(t)                                                             \
  {                                                                           \
    for (int p = 0; p < 8; ++p)                                               \
      pa[p] = *(const f32x4*)(A + (size_t)(p * 16 + arow) * E + (t) * 64 +    \
                              acol * 4);                                      \
    for (int p = 0; p < 4; ++p)                                               \
      pb[p] = ld8(W + (size_t)(n0 + p * 32 + brow) * E + (t) * 64 + bcol * 8);\
  }
#define STORE_T(bs)                                                           \
  {                                                                           \
    for (int p = 0; p < 8; ++p) {                                             \
      bf16x4 av;                                                              \
      for (int e = 0; e < 4; ++e) av[e] = (bf16)pa[p][e];                     \
      *(bf16x4*)&smA[bs][p * 16 + arow][acol * 4] = av;                       \
    }                                                                         \
    for (int p = 0; p < 4; ++p)                                               \
      *(bf16x8*)&smB[bs][p * 32 + brow][bcol * 8] = pb[p];                    \
  }

  LOAD_T(0);
  STORE_T(0);
  LOAD_T(1);
  __syncthreads();

  f32x4 acc[4][4] = {};
  for (int t = 0; t < 8; ++t) {
    const int bs = t & 1;
    bf16x8 af[2][4], bfr[2][4];
    for (int ks = 0; ks < 2; ++ks)
      for (int i = 0; i < 4; ++i)
        af[ks][i] = ld8(&smA[bs][wm * 64 + 16 * i + lrow][ks * 32 + quad * 8]);
    for (int ks = 0; ks < 2; ++ks)
      for (int c = 0; c < 4; ++c)
        bfr[ks][c] = ld8(&smB[bs][wn * 64 + 16 * c + lrow][ks * 32 + quad * 8]);
    for (int ks = 0; ks < 2; ++ks)
      for (int i = 0; i < 4; ++i)
        for (int c = 0; c < 4; ++c)
          acc[i][c] = MFMA16(af[ks][i], bfr[ks][c], acc[i][c]);
    if (t < 7) {
      STORE_T(bs ^ 1);
      if (t < 6) LOAD_T(t + 2);
    }
    __syncthreads();
  }
#undef LOAD_T
#undef STORE_T

  const float qsc = (z == 0) ? QSCALE : 1.f;
  float bvl[4];
  for (int c = 0; c < 4; ++c) bvl[c] = bias[n0 + wn * 64 + 16 * c + lrow];
  bf16* Cs = &smA[0][0][0];  // reuse as [128][136]
  for (int i = 0; i < 4; ++i)
    for (int c = 0; c < 4; ++c)
      for (int r = 0; r < 4; ++r) {
        int row = wm * 64 + 16 * i + 4 * quad + r;
        int col = wn * 64 + 16 * c + lrow;
        bf16 val = (bf16)((acc[i][c][r] + bvl[c]) * qsc);
        if (z < 2) Cs[row * 136 + col] = val;
        else       Cs[col * 136 + row] = val;
      }
  __syncthreads();
  const int rr = tid >> 1, hh = tid & 1;
  if (z == 0) {
    bf16* dstp = qproj + (size_t)(mt * 128 + rr) * E + n0 + hh * 64;
    for (int j = 0; j < 8; ++j)
      *(bf16x8*)(dstp + j * 8) = *(bf16x8*)&Cs[rr * 136 + hh * 64 + j * 8];
  } else if (z == 1) {
    // fragment-major K
    int mtg = mt * 128 + rr;
    int b2 = mtg >> 12, kk = mtg & 4095;
    int t32 = kk >> 5, l31 = kk & 31;
    int bh2 = b2 * 8 + (n0 >> 6) + hh;
    bf16* dstp = kproj + (size_t)bh2 * 262144 + (size_t)t32 * 2048 + l31 * 8;
    for (int j = 0; j < 8; ++j)
      *(bf16x8*)(dstp + j * 256) = *(bf16x8*)&Cs[rr * 136 + hh * 64 + j * 8];
  } else {
    // fragment-major V
    int m0g = mt * 128, b2 = m0g >> 12, kk0 = m0g & 4095;
    int ng = n0 + rr, hd = ng >> 6, d = ng & 63;
    int bh2 = b2 * 8 + hd, dt = d >> 5, l31 = d & 31;
    bf16* dstp = vt + (size_t)bh2 * 262144 + dt * 1024 + l31 * 8;
    for (int j = 0; j < 8; ++j) {
      int kk = kk0 + hh * 64 + 8 * j;
      int t32 = kk >> 5, s = (kk >> 4) & 1, hi2 = (kk >> 3) & 1;
      *(bf16x8*)(dstp + (size_t)t32 * 2048 + s * 512 + hi2 * 256) =
          *(bf16x8*)&Cs[rr * 136 + hh * 64 + j * 8];
    }
  }
}

// ------------- fused flash attention, v8: 8 waves, grid-limited fix --------
// Same zero-LDS fragment-major loop as v7, but blocks are 512 threads: 8
// waves each own a kk-EIGHTH (512 kk = 16 iters) of the same 64q tile.
// Grid stays 512 (2 blocks/CU) so L2 traffic is unchanged (512MB, XCD-
// pinned), but waves/CU doubles to 16 (4/SIMD) -- v7's occupancy was capped
// by its grid (512 blocks x 4 waves = 2/SIMD), not by VGPR (116) or LDS.
// NO min-waves launch bound (r5 lesson: forcing 4/EU caps VGPR at 128 and
// spills). Epilogue: 8-partial two-phase merge through F[8][64][33] f32.
__global__ __launch_bounds__(512) void attn_kernel(
    const bf16* __restrict__ qp, const bf16* __restrict__ kfg,
    const bf16* __restrict__ vfg, bf16* __restrict__ ctx) {
  const int tid = threadIdx.x;
  const int lane = tid & 63, wave = tid >> 6;  // wave = kk-eighth, 0..7
  const int l31 = lane & 31, hi = lane >> 5;
  const int hw = blockIdx.x;
  // 512 blocks = 8 XCD x 64; XCD x hosts bh {2x, 2x+1}
  const int xcd = hw & 7, ii = hw >> 3;
  const int bh = xcd * 2 + (ii >> 5), qt = ii & 31;
  const int b = bh >> 3, h = bh & 7;
  const int q0 = qt * 64;

  // LDS: epilogue only. F[8][64][33] f32 (67584B) + Lr[8][64] f32 (2048B)
  __shared__ __align__(16) char smem[69632];

  // Q B-frags (Q^T cols): qf[t][st]: col q = q0+32t+l31, k=d = st*16+hi*8+j
  bf16x8 qf[2][4];
  for (int t = 0; t < 2; ++t)
    for (int st = 0; st < 4; ++st)
      qf[t][st] = ld8(qp + (size_t)(b * LQ + q0 + 32 * t + l31) * E + h * DH +
                      st * 16 + hi * 8);

  float lp[2] = {0.f, 0.f};   // per-lane row-sum partials (q = q0+32t+l31)
  f32x16 acc[2][2] = {};      // [qtile][dtile]; row=q(map), col=d=l31+32dt

  // per-lane fragment bases; tile index t32 = bh*128 + wave*16 + it
  const size_t tb = ((size_t)bh * 128 + wave * 16) * 2048;
  const bf16* kb = kfg + tb + hi * 256 + l31 * 8;
  const bf16* vb = vfg + tb + hi * 256 + l31 * 8;

  // kf_[st]: K[kk=tile*32+l31][d = st*16+hi*8+e]
  // vf_[dt*2+s]: V^T[d=dt*32+l31][kk = tile*32+s*16+hi*8+e]
#define LOADT(kf_, vf_, it)                                          \
  {                                                                  \
    const bf16* kp_ = kb + (size_t)(it) * 2048;                      \
    kf_[0] = ld8(kp_);                                               \
    kf_[1] = ld8(kp_ + 512);                                         \
    kf_[2] = ld8(kp_ + 1024);                                        \
    kf_[3] = ld8(kp_ + 1536);                                        \
    const bf16* vp_ = vb + (size_t)(it) * 2048;                      \
    vf_[0] = ld8(vp_);                                               \
    vf_[1] = ld8(vp_ + 512);                                         \
    vf_[2] = ld8(vp_ + 1024);                                        \
    vf_[3] = ld8(vp_ + 1536);                                        \
  }

  // one 32kk x 64q step on fragment buffers (all-register)
#define COMPUTE(kf_, vf_)                                            \
  _Pragma("unroll")                                                  \
  for (int t = 0; t < 2; ++t) {                                      \
    f32x16 s_ = {};                                                  \
    __builtin_amdgcn_s_setprio(1);                                   \
    s_ = MFMA32(kf_[0], qf[t][0], s_);                               \
    s_ = MFMA32(kf_[1], qf[t][1], s_);                               \
    s_ = MFMA32(kf_[2], qf[t][2], s_);                               \
    s_ = MFMA32(kf_[3], qf[t][3], s_);                               \
    __builtin_amdgcn_s_setprio(0);                                   \
    unsigned w_[4][2];                                               \
    _Pragma("unroll")                                                \
    for (int t4 = 0; t4 < 4; ++t4)                                   \
      _Pragma("unroll")                                              \
      for (int u = 0; u < 2; ++u) {                                  \
        float e0 = EXP2(s_[4 * t4 + 2 * u]);                         \
        float e1 = EXP2(s_[4 * t4 + 2 * u + 1]);                     \
        lp[t] += e0;                                                 \
        lp[t] += e1;                                                 \
        asm("v_cvt_pk_bf16_f32 %0, %1, %2"                           \
            : "=v"(w_[t4][u])                                        \
            : "v"(e0), "v"(e1));                                     \
      }                                                              \
    bf16x8 paf[2];                                                   \
    _Pragma("unroll")                                                \
    for (int s = 0; s < 2; ++s) {                                    \
      unsigned a0 = w_[2 * s][0], b0 = w_[2 * s + 1][0];             \
      unsigned a1 = w_[2 * s][1], b1 = w_[2 * s + 1][1];             \
      asm("v_permlane32_swap_b32 %0, %1" : "+v"(a0), "+v"(b0));      \
      asm("v_permlane32_swap_b32 %0, %1" : "+v"(a1), "+v"(b1));      \
      u32x4 pw_ = {a0, a1, b0, b1};                                  \
      paf[s] = *(bf16x8*)&pw_;                                       \
    }                                                                \
    __builtin_amdgcn_s_setprio(1);                                   \
    acc[t][0] = MFMA32(paf[0], vf_[0], acc[t][0]);                   \
    acc[t][0] = MFMA32(paf[1], vf_[1], acc[t][0]);                   \
    acc[t][1] = MFMA32(paf[0], vf_[2], acc[t][1]);                   \
    acc[t][1] = MFMA32(paf[1], vf_[3], acc[t][1]);                   \
    __builtin_amdgcn_s_setprio(0);                                   \
  }

  bf16x8 kfA[4], vfA[4], kfB[4], vfB[4];
  LOADT(kfA, vfA, 0);
  for (int it = 0; it < 16; it += 2) {
    LOADT(kfB, vfB, it + 1);   // next tile in flight over COMPUTE(A)
    COMPUTE(kfA, vfA);
    if (it + 2 < 16) LOADT(kfA, vfA, it + 2);
    COMPUTE(kfB, vfB);
  }
#undef LOADT
#undef COMPUTE

  // merge lane-halves of row sums: both halves hold full eighth-sum after
  for (int t = 0; t < 2; ++t) lp[t] += __shfl_xor(lp[t], 32);

  float* F = (float*)smem;             // [8][64][33]
  float* Lr = (float*)(smem + 67584);  // [8][64]
  if (hi == 0) {
    Lr[wave * 64 + l31] = lp[0];
    Lr[wave * 64 + 32 + l31] = lp[1];
  }
  // ---- phase dt=0: publish cols 0..31, merge, store ----
#pragma unroll
  for (int t = 0; t < 2; ++t)
#pragma unroll
    for (int r = 0; r < 16; ++r) {
      int q = 32 * t + (r & 3) + 8 * (r >> 2) + 4 * hi;
      F[(wave * 64 + q) * 33 + l31] = acc[t][0][r];
    }
  __syncthreads();
  const int mq = tid >> 3, d0 = (tid & 7) * 4;
  float ls = 0.f;
#pragma unroll
  for (int w2 = 0; w2 < 8; ++w2) ls += Lr[w2 * 64 + mq];
  const float inv = 1.f / ls;
  {
    float o[4] = {0.f, 0.f, 0.f, 0.f};
#pragma unroll
    for (int w2 = 0; w2 < 8; ++w2) {
      const float* Fr = &F[(w2 * 64 + mq) * 33 + d0];
      for (int j = 0; j < 4; ++j) o[j] += Fr[j];
    }
    bf16x4 ov;
    for (int j = 0; j < 4; ++j) ov[j] = (bf16)(o[j] * inv);
    *(bf16x4*)(ctx + (size_t)(b * LQ + q0 + mq) * E + h * DH + d0) = ov;
  }
  __syncthreads();
  // ---- phase dt=1: publish cols 32..63, merge, store ----
#pragma unroll
  for (int t = 0; t < 2; ++t)
#pragma unroll
    for (int r = 0; r < 16; ++r) {
      int q = 32 * t + (r & 3) + 8 * (r >> 2) + 4 * hi;
      F[(wave * 64 + q) * 33 + l31] = acc[t][1][r];
    }
  __syncthreads();
  {
    float o[4] = {0.f, 0.f, 0.f, 0.f};
#pragma unroll
    for (int w2 = 0; w2 < 8; ++w2) {
      const float* Fr = &F[(w2 * 64 + mq) * 33 + d0];
      for (int j = 0; j < 4; ++j) o[j] += Fr[j];
    }
    bf16x4 ov;
    for (int j = 0; j < 4; ++j) ov[j] = (bf16)(o[j] * inv);
    *(bf16x4*)(ctx + (size_t)(b * LQ + q0 + mq) * E + h * DH + 32 + d0) = ov;
  }
}

// ------------- out-projection GEMM: y = ctx @ Wo^T (f32 out) ---------------
__global__ __launch_bounds__(256) void outgemm_kernel(
    const bf16* __restrict__ Cx, const bf16* __restrict__ Wo,
    float* __restrict__ y) {
  __shared__ bf16 smA[2][128][72];
  __shared__ bf16 smB[2][128][72];
  const int tid = threadIdx.x;
  const int lane = tid & 63, wave = tid >> 6;
  const int lrow = lane & 15, quad = lane >> 4;
  const int wm = wave & 1, wn = wave >> 1;
  const int m0 = blockIdx.x * 128, n0 = blockIdx.y * 128;
  const bf16* A = Cx + (size_t)m0 * E;

  const int srow = tid >> 3, schunk = tid & 7;  // 32 rows x 8 16B-chunks

  bf16x8 pa[4], pb[4];
#define LOAD_T(t)                                                             \
  {                                                                           \
    for (int p = 0; p < 4; ++p)                                               \
      pa[p] = ld8(A + (size_t)(p * 32 + srow) * E + (t) * 64 + schunk * 8);   \
    for (int p = 0; p < 4; ++p)                                               \
      pb[p] = ld8(Wo + (size_t)(n0 + p * 32 + srow) * E + (t) * 64 +          \
                  schunk * 8);                                                \
  }
#define STORE_T(bs)                                                           \
  {                                                                           \
    for (int p = 0; p < 4; ++p)                                               \
      *(bf16x8*)&smA[bs][p * 32 + srow][schunk * 8] = pa[p];                  \
    for (int p = 0; p < 4; ++p)                                               \
      *(bf16x8*)&smB[bs][p * 32 + srow][schunk * 8] = pb[p];                  \
  }

  LOAD_T(0);
  STORE_T(0);
  LOAD_T(1);
  __syncthreads();

  f32x4 acc[4][4] = {};
  for (int t = 0; t < 8; ++t) {
    const int bs = t & 1;
    bf16x8 af[2][4], bfr[2][4];
    for (int ks = 0; ks < 2; ++ks)
      for (int i = 0; i < 4; ++i)
        af[ks][i] = ld8(&smA[bs][wm * 64 + 16 * i + lrow][ks * 32 + quad * 8]);
    for (int ks = 0; ks < 2; ++ks)
      for (int c = 0; c < 4; ++c)
        bfr[ks][c] = ld8(&smB[bs][wn * 64 + 16 * c + lrow][ks * 32 + quad * 8]);
    for (int ks = 0; ks < 2; ++ks)
      for (int i = 0; i < 4; ++i)
        for (int c = 0; c < 4; ++c)
          acc[i][c] = MFMA16(af[ks][i], bfr[ks][c], acc[i][c]);
    if (t < 7) {
      STORE_T(bs ^ 1);
      if (t < 6) LOAD_T(t + 2);
    }
    __syncthreads();
  }
#undef LOAD_T
#undef STORE_T

  for (int i = 0; i < 4; ++i)
    for (int c = 0; c < 4; ++c)
      for (int r = 0; r < 4; ++r) {
        int row = m0 + wm * 64 + 16 * i + 4 * quad + r;
        int col = n0 + wn * 64 + 16 * c + lrow;
        y[(size_t)row * E + col] = acc[i][c][r];
      }
}

// ------------- bias + residual + LayerNorm (memory-bound) ------------------
__global__ __launch_bounds__(256) void ln_kernel(
    const float* __restrict__ y, const float* __restrict__ resid,
    const float* __restrict__ bo, const float* __restrict__ gamma,
    const float* __restrict__ beta, float* __restrict__ out) {
  const int tid = threadIdx.x;
  const int lane = tid & 63, wave = tid >> 6;
  const int row = blockIdx.x * 4 + wave;
  const int c0 = lane * 8;

  const float* yr = y + (size_t)row * E + c0;
  const float* rr = resid + (size_t)row * E + c0;
  f32x4 y0 = *(const f32x4*)yr, y1 = *(const f32x4*)(yr + 4);
  f32x4 r0 = *(const f32x4*)rr, r1 = *(const f32x4*)(rr + 4);
  f32x4 b0 = *(const f32x4*)(bo + c0), b1 = *(const f32x4*)(bo + c0 + 4);

  float xv[8];
  float s1 = 0.f, s2 = 0.f;
  for (int j = 0; j < 4; ++j) {
    xv[j] = y0[j] + r0[j] + b0[j];
    xv[4 + j] = y1[j] + r1[j] + b1[j];
  }
  for (int j = 0; j < 8; ++j) {
    s1 += xv[j];
    s2 += xv[j] * xv[j];
  }
  for (int off = 1; off < 64; off <<= 1) {
    s1 += __shfl_xor(s1, off);
    s2 += __shfl_xor(s2, off);
  }
  const float mean = s1 * (1.f / 512.f);
  const float var = s2 * (1.f / 512.f) - mean * mean;
  const float rstd = rsqrtf(var + 1e-5f);

  f32x4 g0 = *(const f32x4*)(gamma + c0), g1 = *(const f32x4*)(gamma + c0 + 4);
  f32x4 t0 = *(const f32x4*)(beta + c0), t1 = *(const f32x4*)(beta + c0 + 4);
  f32x4 o0, o1;
  for (int j = 0; j < 4; ++j) {
    o0[j] = (xv[j] - mean) * rstd * g0[j] + t0[j];
    o1[j] = (xv[4 + j] - mean) * rstd * g1[j] + t1[j];
  }
  float* op = out + (size_t)row * E + c0;
  *(f32x4*)op = o0;
  *(f32x4*)(op + 4) = o1;
}

extern "C" void kernel_launch(void* const* d_in, const int* in_sizes, int n_in,
                              void* d_out, int out_size, void* d_ws, size_t ws_size,
                              hipStream_t stream) {
  const float* query     = (const float*)d_in[0];
  const float* key_value = (const float*)d_in[1];
  const float* Wq = (const float*)d_in[2];
  const float* bq = (const float*)d_in[3];
  const float* Wk = (const float*)d_in[4];
  const float* bk = (const float*)d_in[5];
  const float* Wv = (const float*)d_in[6];
  const float* bv = (const float*)d_in[7];
  const float* Wo = (const float*)d_in[8];
  const float* bo = (const float*)d_in[9];
  const float* gamma = (const float*)d_in[10];
  const float* beta  = (const float*)d_in[11];
  float* out = (float*)d_out;

  // ws layout: 4 weights bf16 | qproj(=ctx) bf16 | kproj(frag) | vt(frag) | y f32
  bf16* Wb    = (bf16*)d_ws;
  bf16* Wob   = Wb + (size_t)3 * 262144;
  bf16* qproj = Wb + (size_t)4 * 262144;
  bf16* kproj = qproj + (size_t)4096 * 512;
  bf16* vt    = kproj + (size_t)8192 * 512;
  float* y    = (float*)(vt + (size_t)8192 * 512);

  cvt4_kernel<<<dim3(256, 4), 256, 0, stream>>>(Wq, Wk, Wv, Wo, Wb);
  proj_gemm_kernel<<<dim3(160, 4), 256, 0, stream>>>(
      query, key_value, Wb, bq, bk, bv, qproj, kproj, vt);
  attn_kernel<<<512, 512, 0, stream>>>(qproj, kproj, vt, qproj /*ctx in-place*/);
  outgemm_kernel<<<dim3(32, 4), 256, 0, stream>>>(qproj, Wob, y);
  ln_kernel<<<1024, 256, 0, stream>>>(y, query, bo, gamma, beta, out);
}

// Round 11
// 167.282 us; speedup vs baseline: 1.0023x; 1.0023x over previous
//
#include <hip/hip_runtime.h>
#include <hip/hip_bf16.h>

typedef __bf16 bf16;
typedef __bf16 bf16x8 __attribute__((ext_vector_type(8)));
typedef __bf16 bf16x4 __attribute__((ext_vector_type(4)));
typedef float f32x4 __attribute__((ext_vector_type(4)));
typedef float f32x16 __attribute__((ext_vector_type(16)));
typedef unsigned int u32x4 __attribute__((ext_vector_type(4)));

#define MFMA16(a, b, c) __builtin_amdgcn_mfma_f32_16x16x32_bf16((a), (b), (c), 0, 0, 0)
#define MFMA32(a, b, c) __builtin_amdgcn_mfma_f32_32x32x16_bf16((a), (b), (c), 0, 0, 0)

constexpr int LQ = 2048, LK = 4096, E = 512, H = 8, DH = 64;
// q pre-scale: 1/sqrt(DH) * log2(e) folded into q-projection epilogue
#define QSCALE 0.1803368801111137f

#if __has_builtin(__builtin_amdgcn_exp2f)
#define EXP2(x) __builtin_amdgcn_exp2f(x)
#else
#define EXP2(x) __expf(0.6931471805599453f * (x))
#endif

__device__ __forceinline__ bf16x8 ld8(const bf16* p) { return *(const bf16x8*)p; }

// ------------- fp32 -> bf16 conversion of the 4 weight matrices ------------
__global__ __launch_bounds__(256) void cvt4_kernel(
    const float* __restrict__ w0, const float* __restrict__ w1,
    const float* __restrict__ w2, const float* __restrict__ w3,
    bf16* __restrict__ dst) {
  const float* srcs[4] = {w0, w1, w2, w3};
  const float* src = srcs[blockIdx.y];
  bf16* d = dst + (size_t)blockIdx.y * 262144;
  int i = (blockIdx.x * 256 + threadIdx.x) * 4;
  f32x4 v = *(const f32x4*)(src + i);
  bf16x4 o;
  for (int j = 0; j < 4; ++j) o[j] = (bf16)v[j];
  *(bf16x4*)(d + i) = o;
}

// ------------- q/k/v projection: SINGLE-buffer LDS, 4 blocks/CU -----------
// r10 diagnosis: 640 blocks at 72KB LDS = 2 blocks/CU = 512 slots -> TWO
// dispatch rounds (512 + 128) => dur ~ 2x per-block time. Single-buffered
// 36.9KB LDS fits 4 blocks/CU -> all 640 in one round. 2 barriers/iter
// (frag-reads-drained, stores-visible); distance-2 register prefetch kept.
// K and V are written FRAGMENT-MAJOR for the attn kernel's 32x32 MFMAs:
//  Kf[bh][t32][j=st*2+hi][l31][e]  (elem = K[kk=t32*32+l31][d=j*8+e])
//  Vf[bh][t32][dt][s][hi][l31][e]  (elem = V[kk=t32*32+s*16+hi*8+e][d=dt*32+l31])
__global__ __launch_bounds__(256) void proj_gemm_kernel(
    const float* __restrict__ query, const float* __restrict__ kv,
    const bf16* __restrict__ Wall,
    const float* __restrict__ bq, const float* __restrict__ bk,
    const float* __restrict__ bv,
    bf16* __restrict__ qproj, bf16* __restrict__ kproj, bf16* __restrict__ vt) {
  // union: loop smA[128][72] + smB[128][72] bf16 (36864B); epi Cs[128][136]
  __shared__ __align__(16) char smem[36864];
  typedef bf16 RowT[72];
  RowT* smA = (RowT*)smem;             // [128]
  RowT* smB = (RowT*)(smem + 18432);   // [128]

  const int tid = threadIdx.x;
  const int lane = tid & 63, wave = tid >> 6;
  const int lrow = lane & 15, quad = lane >> 4;
  const int wm = wave & 1, wn = wave >> 1;

  int x = blockIdx.x, z, mt;
  if (x < 32) { z = 0; mt = x; }
  else if (x < 96) { z = 1; mt = x - 32; }
  else { z = 2; mt = x - 96; }
  const float* A = ((z == 0) ? query : kv) + (size_t)mt * 128 * E;
  const bf16* W = Wall + (size_t)z * 262144;
  const float* bias = (z == 0) ? bq : (z == 1) ? bk : bv;
  const int n0 = blockIdx.y * 128;

  const int arow = tid >> 4, acol = tid & 15;
  const int brow = tid >> 3, bcol = tid & 7;

  f32x4 pa[8];
  bf16x8 pb[4];
#define LOAD_T(t)                                                             \
  {                                                                           \
    for (int p = 0; p < 8; ++p)                                               \
      pa[p] = *(const f32x4*)(A + (size_t)(p * 16 + arow) * E + (t) * 64 +    \
                              acol * 4);                                      \
    for (int p = 0; p < 4; ++p)                                               \
      pb[p] = ld8(W + (size_t)(n0 + p * 32 + brow) * E + (t) * 64 + bcol * 8);\
  }
#define STORE_T()                                                             \
  {                                                                           \
    for (int p = 0; p < 8; ++p) {                                             \
      bf16x4 av;                                                              \
      for (int e = 0; e < 4; ++e) av[e] = (bf16)pa[p][e];                     \
      *(bf16x4*)&smA[p * 16 + arow][acol * 4] = av;                           \
    }                                                                         \
    for (int p = 0; p < 4; ++p)                                               \
      *(bf16x8*)&smB[p * 32 + brow][bcol * 8] = pb[p];                        \
  }

  LOAD_T(0);
  STORE_T();
  LOAD_T(1);          // prefetch tile 1 into regs
  __syncthreads();    // tile 0 visible

  f32x4 acc[4][4] = {};
  for (int t = 0; t < 8; ++t) {
    bf16x8 af[2][4], bfr[2][4];
    for (int ks = 0; ks < 2; ++ks)
      for (int i = 0; i < 4; ++i)
        af[ks][i] = ld8(&smA[wm * 64 + 16 * i + lrow][ks * 32 + quad * 8]);
    for (int ks = 0; ks < 2; ++ks)
      for (int c = 0; c < 4; ++c)
        bfr[ks][c] = ld8(&smB[wn * 64 + 16 * c + lrow][ks * 32 + quad * 8]);
    for (int ks = 0; ks < 2; ++ks)
      for (int i = 0; i < 4; ++i)
        for (int c = 0; c < 4; ++c)
          acc[i][c] = MFMA16(af[ks][i], bfr[ks][c], acc[i][c]);
    if (t < 7) {
      __syncthreads();            // all waves' frag reads drained
      STORE_T();                  // tile t+1 from prefetch regs
      if (t < 6) LOAD_T(t + 2);   // distance-2 prefetch
      __syncthreads();            // tile t+1 visible
    }
  }
#undef LOAD_T
#undef STORE_T

  const float qsc = (z == 0) ? QSCALE : 1.f;
  float bvl[4];
  for (int c = 0; c < 4; ++c) bvl[c] = bias[n0 + wn * 64 + 16 * c + lrow];
  __syncthreads();  // loop LDS dead before epilogue reuse
  bf16* Cs = (bf16*)smem;  // reuse as [128][136] (34816 <= 36864)
  for (int i = 0; i < 4; ++i)
    for (int c = 0; c < 4; ++c)
      for (int r = 0; r < 4; ++r) {
        int row = wm * 64 + 16 * i + 4 * quad + r;
        int col = wn * 64 + 16 * c + lrow;
        bf16 val = (bf16)((acc[i][c][r] + bvl[c]) * qsc);
        if (z < 2) Cs[row * 136 + col] = val;
        else       Cs[col * 136 + row] = val;
      }
  __syncthreads();
  const int rr = tid >> 1, hh = tid & 1;
  if (z == 0) {
    bf16* dstp = qproj + (size_t)(mt * 128 + rr) * E + n0 + hh * 64;
    for (int j = 0; j < 8; ++j)
      *(bf16x8*)(dstp + j * 8) = *(bf16x8*)&Cs[rr * 136 + hh * 64 + j * 8];
  } else if (z == 1) {
    // fragment-major K
    int mtg = mt * 128 + rr;
    int b2 = mtg >> 12, kk = mtg & 4095;
    int t32 = kk >> 5, l31 = kk & 31;
    int bh2 = b2 * 8 + (n0 >> 6) + hh;
    bf16* dstp = kproj + (size_t)bh2 * 262144 + (size_t)t32 * 2048 + l31 * 8;
    for (int j = 0; j < 8; ++j)
      *(bf16x8*)(dstp + j * 256) = *(bf16x8*)&Cs[rr * 136 + hh * 64 + j * 8];
  } else {
    // fragment-major V
    int m0g = mt * 128, b2 = m0g >> 12, kk0 = m0g & 4095;
    int ng = n0 + rr, hd = ng >> 6, d = ng & 63;
    int bh2 = b2 * 8 + hd, dt = d >> 5, l31 = d & 31;
    bf16* dstp = vt + (size_t)bh2 * 262144 + dt * 1024 + l31 * 8;
    for (int j = 0; j < 8; ++j) {
      int kk = kk0 + hh * 64 + 8 * j;
      int t32 = kk >> 5, s = (kk >> 4) & 1, hi2 = (kk >> 3) & 1;
      *(bf16x8*)(dstp + (size_t)t32 * 2048 + s * 512 + hi2 * 256) =
          *(bf16x8*)&Cs[rr * 136 + hh * 64 + j * 8];
    }
  }
}

// ------------- fused flash attention, v7 (r9 form): fragment-major K/V -----
// 512 blocks x 4 waves, 64q/wave, kk-quarters, XCD-pinned 512MB L2 stream,
// ZERO LDS in the loop: K/V live in workspace in fragment-major layout
// (written by proj), so every fragment load is a lane-linear contiguous 1KB
// global_load_dwordx4 (ideal coalescing, L2-hit). Register double-buffer one
// iteration ahead covers L2 latency. P stays in registers via cvt_pk_bf16 +
// permlane32_swap. Epilogue LDS 34.8KB (two d-phases).
__global__ __launch_bounds__(256, 2) void attn_kernel(
    const bf16* __restrict__ qp, const bf16* __restrict__ kfg,
    const bf16* __restrict__ vfg, bf16* __restrict__ ctx) {
  const int tid = threadIdx.x;
  const int lane = tid & 63, wave = tid >> 6;  // wave = kk-quarter
  const int l31 = lane & 31, hi = lane >> 5;
  const int hw = blockIdx.x;
  // 512 blocks = 8 XCD x 64; XCD x hosts bh {2x, 2x+1}
  const int xcd = hw & 7, ii = hw >> 3;
  const int bh = xcd * 2 + (ii >> 5), qt = ii & 31;
  const int b = bh >> 3, h = bh & 7;
  const int q0 = qt * 64;

  // LDS: epilogue only. F[4][64][33] f32 (33792B) + Lr[4][64] f32 (1024B)
  __shared__ __align__(16) char smem[34816];

  // Q B-frags (Q^T cols): qf[t][st]: col q = q0+32t+l31, k=d = st*16+hi*8+j
  bf16x8 qf[2][4];
  for (int t = 0; t < 2; ++t)
    for (int st = 0; st < 4; ++st)
      qf[t][st] = ld8(qp + (size_t)(b * LQ + q0 + 32 * t + l31) * E + h * DH +
                      st * 16 + hi * 8);

  float lp[2] = {0.f, 0.f};   // per-lane row-sum partials (q = q0+32t+l31)
  f32x16 acc[2][2] = {};      // [qtile][dtile]; row=q(map), col=d=l31+32dt

  // per-lane fragment bases; tile index t32 = bh*128 + wave*32 + it
  const size_t tb = ((size_t)bh * 128 + wave * 32) * 2048;
  const bf16* kb = kfg + tb + hi * 256 + l31 * 8;
  const bf16* vb = vfg + tb + hi * 256 + l31 * 8;

  // kf_[st]: K[kk=tile*32+l31][d = st*16+hi*8+e]
  // vf_[dt*2+s]: V^T[d=dt*32+l31][kk = tile*32+s*16+hi*8+e]
#define LOADT(kf_, vf_, it)                                          \
  {                                                                  \
    const bf16* kp_ = kb + (size_t)(it) * 2048;                      \
    kf_[0] = ld8(kp_);                                               \
    kf_[1] = ld8(kp_ + 512);                                         \
    kf_[2] = ld8(kp_ + 1024);                                        \
    kf_[3] = ld8(kp_ + 1536);                                        \
    const bf16* vp_ = vb + (size_t)(it) * 2048;                      \
    vf_[0] = ld8(vp_);                                               \
    vf_[1] = ld8(vp_ + 512);                                         \
    vf_[2] = ld8(vp_ + 1024);                                        \
    vf_[3] = ld8(vp_ + 1536);                                        \
  }

  // one 32kk x 64q step on fragment buffers (all-register)
#define COMPUTE(kf_, vf_)                                            \
  _Pragma("unroll")                                                  \
  for (int t = 0; t < 2; ++t) {                                      \
    f32x16 s_ = {};                                                  \
    __builtin_amdgcn_s_setprio(1);                                   \
    s_ = MFMA32(kf_[0], qf[t][0], s_);                               \
    s_ = MFMA32(kf_[1], qf[t][1], s_);                               \
    s_ = MFMA32(kf_[2], qf[t][2], s_);                               \
    s_ = MFMA32(kf_[3], qf[t][3], s_);                               \
    __builtin_amdgcn_s_setprio(0);                                   \
    unsigned w_[4][2];                                               \
    _Pragma("unroll")                                                \
    for (int t4 = 0; t4 < 4; ++t4)                                   \
      _Pragma("unroll")                                              \
      for (int u = 0; u < 2; ++u) {                                  \
        float e0 = EXP2(s_[4 * t4 + 2 * u]);                         \
        float e1 = EXP2(s_[4 * t4 + 2 * u + 1]);                     \
        lp[t] += e0;                                                 \
        lp[t] += e1;                                                 \
        asm("v_cvt_pk_bf16_f32 %0, %1, %2"                           \
            : "=v"(w_[t4][u])                                        \
            : "v"(e0), "v"(e1));                                     \
      }                                                              \
    bf16x8 paf[2];                                                   \
    _Pragma("unroll")                                                \
    for (int s = 0; s < 2; ++s) {                                    \
      unsigned a0 = w_[2 * s][0], b0 = w_[2 * s + 1][0];             \
      unsigned a1 = w_[2 * s][1], b1 = w_[2 * s + 1][1];             \
      asm("v_permlane32_swap_b32 %0, %1" : "+v"(a0), "+v"(b0));      \
      asm("v_permlane32_swap_b32 %0, %1" : "+v"(a1), "+v"(b1));      \
      u32x4 pw_ = {a0, a1, b0, b1};                                  \
      paf[s] = *(bf16x8*)&pw_;                                       \
    }                                                                \
    __builtin_amdgcn_s_setprio(1);                                   \
    acc[t][0] = MFMA32(paf[0], vf_[0], acc[t][0]);                   \
    acc[t][0] = MFMA32(paf[1], vf_[1], acc[t][0]);                   \
    acc[t][1] = MFMA32(paf[0], vf_[2], acc[t][1]);                   \
    acc[t][1] = MFMA32(paf[1], vf_[3], acc[t][1]);                   \
    __builtin_amdgcn_s_setprio(0);                                   \
  }

  bf16x8 kfA[4], vfA[4], kfB[4], vfB[4];
  LOADT(kfA, vfA, 0);
  for (int it = 0; it < 32; it += 2) {
    LOADT(kfB, vfB, it + 1);   // next tile in flight over COMPUTE(A)
    COMPUTE(kfA, vfA);
    if (it + 2 < 32) LOADT(kfA, vfA, it + 2);
    COMPUTE(kfB, vfB);
  }
#undef LOADT
#undef COMPUTE

  // merge lane-halves of row sums: both halves hold full quarter-sum after
  for (int t = 0; t < 2; ++t) lp[t] += __shfl_xor(lp[t], 32);

  float* F = (float*)smem;             // [4][64][33]
  float* Lr = (float*)(smem + 33792);  // [4][64]
  if (hi == 0) {
    Lr[wave * 64 + l31] = lp[0];
    Lr[wave * 64 + 32 + l31] = lp[1];
  }
  // ---- phase dt=0: publish cols 0..31, merge, store ----
#pragma unroll
  for (int t = 0; t < 2; ++t)
#pragma unroll
    for (int r = 0; r < 16; ++r) {
      int q = 32 * t + (r & 3) + 8 * (r >> 2) + 4 * hi;
      F[(wave * 64 + q) * 33 + l31] = acc[t][0][r];
    }
  __syncthreads();
  const int mq = tid >> 2, d0 = (tid & 3) * 8;
  float ls = Lr[mq] + Lr[64 + mq] + Lr[128 + mq] + Lr[192 + mq];
  const float inv = 1.f / ls;
  {
    float o[8] = {};
#pragma unroll
    for (int w2 = 0; w2 < 4; ++w2) {
      const float* Fr = &F[(w2 * 64 + mq) * 33 + d0];
      for (int j = 0; j < 8; ++j) o[j] += Fr[j];
    }
    bf16x8 ov;
    for (int j = 0; j < 8; ++j) ov[j] = (bf16)(o[j] * inv);
    *(bf16x8*)(ctx + (size_t)(b * LQ + q0 + mq) * E + h * DH + d0) = ov;
  }
  __syncthreads();
  // ---- phase dt=1: publish cols 32..63, merge, store ----
#pragma unroll
  for (int t = 0; t < 2; ++t)
#pragma unroll
    for (int r = 0; r < 16; ++r) {
      int q = 32 * t + (r & 3) + 8 * (r >> 2) + 4 * hi;
      F[(wave * 64 + q) * 33 + l31] = acc[t][1][r];
    }
  __syncthreads();
  {
    float o[8] = {};
#pragma unroll
    for (int w2 = 0; w2 < 4; ++w2) {
      const float* Fr = &F[(w2 * 64 + mq) * 33 + d0];
      for (int j = 0; j < 8; ++j) o[j] += Fr[j];
    }
    bf16x8 ov;
    for (int j = 0; j < 8; ++j) ov[j] = (bf16)(o[j] * inv);
    *(bf16x8*)(ctx + (size_t)(b * LQ + q0 + mq) * E + h * DH + 32 + d0) = ov;
  }
}

// ------------- out-projection GEMM: y = ctx @ Wo^T (f32 out) ---------------
__global__ __launch_bounds__(256) void outgemm_kernel(
    const bf16* __restrict__ Cx, const bf16* __restrict__ Wo,
    float* __restrict__ y) {
  __shared__ bf16 smA[2][128][72];
  __shared__ bf16 smB[2][128][72];
  const int tid = threadIdx.x;
  const int lane = tid & 63, wave = tid >> 6;
  const int lrow = lane & 15, quad = lane >> 4;
  const int wm = wave & 1, wn = wave >> 1;
  const int m0 = blockIdx.x * 128, n0 = blockIdx.y * 128;
  const bf16* A = Cx + (size_t)m0 * E;

  const int srow = tid >> 3, schunk = tid & 7;  // 32 rows x 8 16B-chunks

  bf16x8 pa[4], pb[4];
#define LOAD_T(t)                                                             \
  {                                                                           \
    for (int p = 0; p < 4; ++p)                                               \
      pa[p] = ld8(A + (size_t)(p * 32 + srow) * E + (t) * 64 + schunk * 8);   \
    for (int p = 0; p < 4; ++p)                                               \
      pb[p] = ld8(Wo + (size_t)(n0 + p * 32 + srow) * E + (t) * 64 +          \
                  schunk * 8);                                                \
  }
#define STORE_T(bs)                                                           \
  {                                                                           \
    for (int p = 0; p < 4; ++p)                                               \
      *(bf16x8*)&smA[bs][p * 32 + srow][schunk * 8] = pa[p];                  \
    for (int p = 0; p < 4; ++p)                                               \
      *(bf16x8*)&smB[bs][p * 32 + srow][schunk * 8] = pb[p];                  \
  }

  LOAD_T(0);
  STORE_T(0);
  LOAD_T(1);
  __syncthreads();

  f32x4 acc[4][4] = {};
  for (int t = 0; t < 8; ++t) {
    const int bs = t & 1;
    bf16x8 af[2][4], bfr[2][4];
    for (int ks = 0; ks < 2; ++ks)
      for (int i = 0; i < 4; ++i)
        af[ks][i] = ld8(&smA[bs][wm * 64 + 16 * i + lrow][ks * 32 + quad * 8]);
    for (int ks = 0; ks < 2; ++ks)
      for (int c = 0; c < 4; ++c)
        bfr[ks][c] = ld8(&smB[bs][wn * 64 + 16 * c + lrow][ks * 32 + quad * 8]);
    for (int ks = 0; ks < 2; ++ks)
      for (int i = 0; i < 4; ++i)
        for (int c = 0; c < 4; ++c)
          acc[i][c] = MFMA16(af[ks][i], bfr[ks][c], acc[i][c]);
    if (t < 7) {
      STORE_T(bs ^ 1);
      if (t < 6) LOAD_T(t + 2);
    }
    __syncthreads();
  }
#undef LOAD_T
#undef STORE_T

  for (int i = 0; i < 4; ++i)
    for (int c = 0; c < 4; ++c)
      for (int r = 0; r < 4; ++r) {
        int row = m0 + wm * 64 + 16 * i + 4 * quad + r;
        int col = n0 + wn * 64 + 16 * c + lrow;
        y[(size_t)row * E + col] = acc[i][c][r];
      }
}

// ------------- bias + residual + LayerNorm (memory-bound) ------------------
__global__ __launch_bounds__(256) void ln_kernel(
    const float* __restrict__ y, const float* __restrict__ resid,
    const float* __restrict__ bo, const float* __restrict__ gamma,
    const float* __restrict__ beta, float* __restrict__ out) {
  const int tid = threadIdx.x;
  const int lane = tid & 63, wave = tid >> 6;
  const int row = blockIdx.x * 4 + wave;
  const int c0 = lane * 8;

  const float* yr = y + (size_t)row * E + c0;
  const float* rr = resid + (size_t)row * E + c0;
  f32x4 y0 = *(const f32x4*)yr, y1 = *(const f32x4*)(yr + 4);
  f32x4 r0 = *(const f32x4*)rr, r1 = *(const f32x4*)(rr + 4);
  f32x4 b0 = *(const f32x4*)(bo + c0), b1 = *(const f32x4*)(bo + c0 + 4);

  float xv[8];
  float s1 = 0.f, s2 = 0.f;
  for (int j = 0; j < 4; ++j) {
    xv[j] = y0[j] + r0[j] + b0[j];
    xv[4 + j] = y1[j] + r1[j] + b1[j];
  }
  for (int j = 0; j < 8; ++j) {
    s1 += xv[j];
    s2 += xv[j] * xv[j];
  }
  for (int off = 1; off < 64; off <<= 1) {
    s1 += __shfl_xor(s1, off);
    s2 += __shfl_xor(s2, off);
  }
  const float mean = s1 * (1.f / 512.f);
  const float var = s2 * (1.f / 512.f) - mean * mean;
  const float rstd = rsqrtf(var + 1e-5f);

  f32x4 g0 = *(const f32x4*)(gamma + c0), g1 = *(const f32x4*)(gamma + c0 + 4);
  f32x4 t0 = *(const f32x4*)(beta + c0), t1 = *(const f32x4*)(beta + c0 + 4);
  f32x4 o0, o1;
  for (int j = 0; j < 4; ++j) {
    o0[j] = (xv[j] - mean) * rstd * g0[j] + t0[j];
    o1[j] = (xv[4 + j] - mean) * rstd * g1[j] + t1[j];
  }
  float* op = out + (size_t)row * E + c0;
  *(f32x4*)op = o0;
  *(f32x4*)(op + 4) = o1;
}

extern "C" void kernel_launch(void* const* d_in, const int* in_sizes, int n_in,
                              void* d_out, int out_size, void* d_ws, size_t ws_size,
                              hipStream_t stream) {
  const float* query     = (const float*)d_in[0];
  const float* key_value = (const float*)d_in[1];
  const float* Wq = (const float*)d_in[2];
  const float* bq = (const float*)d_in[3];
  const float* Wk = (const float*)d_in[4];
  const float* bk = (const float*)d_in[5];
  const float* Wv = (const float*)d_in[6];
  const float* bv = (const float*)d_in[7];
  const float* Wo = (const float*)d_in[8];
  const float* bo = (const float*)d_in[9];
  const float* gamma = (const float*)d_in[10];
  const float* beta  = (const float*)d_in[11];
  float* out = (float*)d_out;

  // ws layout: 4 weights bf16 | qproj(=ctx) bf16 | kproj(frag) | vt(frag) | y f32
  bf16* Wb    = (bf16*)d_ws;
  bf16* Wob   = Wb + (size_t)3 * 262144;
  bf16* qproj = Wb + (size_t)4 * 262144;
  bf16* kproj = qproj + (size_t)4096 * 512;
  bf16* vt    = kproj + (size_t)8192 * 512;
  float* y    = (float*)(vt + (size_t)8192 * 512);

  cvt4_kernel<<<dim3(256, 4), 256, 0, stream>>>(Wq, Wk, Wv, Wo, Wb);
  proj_gemm_kernel<<<dim3(160, 4), 256, 0, stream>>>(
      query, key_value, Wb, bq, bk, bv, qproj, kproj, vt);
  attn_kernel<<<512, 256, 0, stream>>>(qproj, kproj, vt, qproj /*ctx in-place*/);
  outgemm_kernel<<<dim3(32, 4), 256, 0, stream>>>(qproj, Wob, y);
  ln_kernel<<<1024, 256, 0, stream>>>(y, query, bo, gamma, beta, out);
}

// Round 13
// 160.310 us; speedup vs baseline: 1.0459x; 1.0435x over previous
//
#include <hip/hip_runtime.h>
#include <hip/hip_bf16.h>

typedef __bf16 bf16;
typedef __bf16 bf16x8 __attribute__((ext_vector_type(8)));
typedef __bf16 bf16x4 __attribute__((ext_vector_type(4)));
typedef float f32x4 __attribute__((ext_vector_type(4)));
typedef float f32x16 __attribute__((ext_vector_type(16)));
typedef unsigned int u32x4 __attribute__((ext_vector_type(4)));

#define MFMA16(a, b, c) __builtin_amdgcn_mfma_f32_16x16x32_bf16((a), (b), (c), 0, 0, 0)
#define MFMA32(a, b, c) __builtin_amdgcn_mfma_f32_32x32x16_bf16((a), (b), (c), 0, 0, 0)

constexpr int LQ = 2048, LK = 4096, E = 512, H = 8, DH = 64;
// q pre-scale: 1/sqrt(DH) * log2(e) folded into q-projection epilogue
#define QSCALE 0.1803368801111137f

#if __has_builtin(__builtin_amdgcn_exp2f)
#define EXP2(x) __builtin_amdgcn_exp2f(x)
#else
#define EXP2(x) __expf(0.6931471805599453f * (x))
#endif

__device__ __forceinline__ bf16x8 ld8(const bf16* p) { return *(const bf16x8*)p; }

// ------- fp32 -> bf16 conversion of the 4 weights, B-FRAGMENT-MAJOR -------
// Wf[z][n16][k32][lane][e] = W[z][n16*16 + (lane&15)][k32*32 + (lane>>4)*8 + e]
// so GEMM B-frag loads are lane-linear contiguous 1KB global loads (no smB).
__global__ __launch_bounds__(256) void cvt4f_kernel(
    const float* __restrict__ w0, const float* __restrict__ w1,
    const float* __restrict__ w2, const float* __restrict__ w3,
    bf16* __restrict__ dst) {
  int gid = blockIdx.x * 256 + threadIdx.x;  // 131072 = 4 * 512rows * 64cc
  int z = gid >> 15;
  int rem = gid & 32767;
  int row = rem >> 6, cc = rem & 63;  // row 0..511, col-chunk(8) 0..63
  const float* srcs[4] = {w0, w1, w2, w3};
  const float* s = srcs[z] + row * 512 + cc * 8;
  f32x4 v0 = *(const f32x4*)s, v1 = *(const f32x4*)(s + 4);
  bf16x8 o;
  for (int j = 0; j < 4; ++j) {
    o[j] = (bf16)v0[j];
    o[4 + j] = (bf16)v1[j];
  }
  int n16 = row >> 4, lrow = row & 15, k32 = cc >> 2, quad = cc & 3;
  int slot = (n16 * 16 + k32) * 64 + quad * 16 + lrow;
  *(bf16x8*)(dst + (size_t)z * 262144 + (size_t)slot * 8) = o;
}

// ------------- q/k/v projection: A-only LDS (36KB), B-frags direct --------
// smB removed (W is frag-major in workspace): LDS 72->36KB => 3 blocks/CU =>
// all 640 blocks in ONE dispatch round (was two). 1 barrier/iter kept; B-frag
// loads for t+1 issue after the MFMAs and fly across the barrier (L2-hit).
// K and V are written FRAGMENT-MAJOR for the attn kernel's 32x32 MFMAs:
//  Kf[bh][t32][j=st*2+hi][l31][e]  (elem = K[kk=t32*32+l31][d=j*8+e])
//  Vf[bh][t32][dt][s][hi][l31][e]  (elem = V[kk=t32*32+s*16+hi*8+e][d=dt*32+l31])
__global__ __launch_bounds__(256, 3) void proj_gemm_kernel(
    const float* __restrict__ query, const float* __restrict__ kv,
    const bf16* __restrict__ Wall,
    const float* __restrict__ bq, const float* __restrict__ bk,
    const float* __restrict__ bv,
    bf16* __restrict__ qproj, bf16* __restrict__ kproj, bf16* __restrict__ vt) {
  // union: loop smA[2][128][72] (36864B) | epilogue Cs[128][136] (34816B)
  __shared__ __align__(16) char smem[36864];
  typedef bf16 RowT[72];
  RowT* smA0 = (RowT*)smem;
  RowT* smA1 = (RowT*)(smem + 18432);

  const int tid = threadIdx.x;
  const int lane = tid & 63, wave = tid >> 6;
  const int lrow = lane & 15, quad = lane >> 4;
  const int wm = wave & 1, wn = wave >> 1;

  int x = blockIdx.x, z, mt;
  if (x < 32) { z = 0; mt = x; }
  else if (x < 96) { z = 1; mt = x - 32; }
  else { z = 2; mt = x - 96; }
  const float* A = ((z == 0) ? query : kv) + (size_t)mt * 128 * E;
  const float* bias = (z == 0) ? bq : (z == 1) ? bk : bv;
  const int n0 = blockIdx.y * 128;

  const bf16* wb = Wall + (size_t)z * 262144 + (size_t)lane * 8;
  const int n16b = (n0 >> 4) + wn * 4;

  const int arow = tid >> 4, acol = tid & 15;

  f32x4 pa[8];
  bf16x8 bfr[2][4];
#define LOAD_A(t)                                                             \
  for (int p = 0; p < 8; ++p)                                                 \
    pa[p] = *(const f32x4*)(A + (size_t)(p * 16 + arow) * E + (t) * 64 +      \
                            acol * 4);
#define STORE_A(bs)                                                           \
  {                                                                           \
    RowT* sm_ = (bs) ? smA1 : smA0;                                           \
    for (int p = 0; p < 8; ++p) {                                             \
      bf16x4 av;                                                              \
      for (int e = 0; e < 4; ++e) av[e] = (bf16)pa[p][e];                     \
      *(bf16x4*)&sm_[p * 16 + arow][acol * 4] = av;                           \
    }                                                                         \
  }
#define LOAD_B(t)                                                             \
  for (int ks = 0; ks < 2; ++ks)                                              \
    for (int c = 0; c < 4; ++c)                                               \
      bfr[ks][c] =                                                            \
          ld8(wb + (size_t)((n16b + c) * 16 + 2 * (t) + ks) * 512);

  LOAD_A(0);
  STORE_A(0);
  LOAD_A(1);
  LOAD_B(0);
  __syncthreads();

  f32x4 acc[4][4] = {};
  for (int t = 0; t < 8; ++t) {
    const int bs = t & 1;
    RowT* sm_ = bs ? smA1 : smA0;
    bf16x8 af[2][4];
    for (int ks = 0; ks < 2; ++ks)
      for (int i = 0; i < 4; ++i)
        af[ks][i] = ld8(&sm_[wm * 64 + 16 * i + lrow][ks * 32 + quad * 8]);
    for (int ks = 0; ks < 2; ++ks)
      for (int i = 0; i < 4; ++i)
        for (int c = 0; c < 4; ++c)
          acc[i][c] = MFMA16(af[ks][i], bfr[ks][c], acc[i][c]);
    if (t < 7) {
      LOAD_B(t + 1);              // in flight across the barrier (L2-hit)
      STORE_A(bs ^ 1);            // tile t+1 from prefetch regs
      if (t < 6) LOAD_A(t + 2);   // distance-2 prefetch
    }
    __syncthreads();
  }
#undef LOAD_A
#undef STORE_A
#undef LOAD_B

  const float qsc = (z == 0) ? QSCALE : 1.f;
  float bvl[4];
  for (int c = 0; c < 4; ++c) bvl[c] = bias[n0 + wn * 64 + 16 * c + lrow];
  bf16* Cs = (bf16*)smem;  // reuse as [128][136]
  for (int i = 0; i < 4; ++i)
    for (int c = 0; c < 4; ++c)
      for (int r = 0; r < 4; ++r) {
        int row = wm * 64 + 16 * i + 4 * quad + r;
        int col = wn * 64 + 16 * c + lrow;
        bf16 val = (bf16)((acc[i][c][r] + bvl[c]) * qsc);
        if (z < 2) Cs[row * 136 + col] = val;
        else       Cs[col * 136 + row] = val;
      }
  __syncthreads();
  const int rr = tid >> 1, hh = tid & 1;
  if (z == 0) {
    bf16* dstp = qproj + (size_t)(mt * 128 + rr) * E + n0 + hh * 64;
    for (int j = 0; j < 8; ++j)
      *(bf16x8*)(dstp + j * 8) = *(bf16x8*)&Cs[rr * 136 + hh * 64 + j * 8];
  } else if (z == 1) {
    // fragment-major K
    int mtg = mt * 128 + rr;
    int b2 = mtg >> 12, kk = mtg & 4095;
    int t32 = kk >> 5, l31 = kk & 31;
    int bh2 = b2 * 8 + (n0 >> 6) + hh;
    bf16* dstp = kproj + (size_t)bh2 * 262144 + (size_t)t32 * 2048 + l31 * 8;
    for (int j = 0; j < 8; ++j)
      *(bf16x8*)(dstp + j * 256) = *(bf16x8*)&Cs[rr * 136 + hh * 64 + j * 8];
  } else {
    // fragment-major V
    int m0g = mt * 128, b2 = m0g >> 12, kk0 = m0g & 4095;
    int ng = n0 + rr, hd = ng >> 6, d = ng & 63;
    int bh2 = b2 * 8 + hd, dt = d >> 5, l31 = d & 31;
    bf16* dstp = vt + (size_t)bh2 * 262144 + dt * 1024 + l31 * 8;
    for (int j = 0; j < 8; ++j) {
      int kk = kk0 + hh * 64 + 8 * j;
      int t32 = kk >> 5, s = (kk >> 4) & 1, hi2 = (kk >> 3) & 1;
      *(bf16x8*)(dstp + (size_t)t32 * 2048 + s * 512 + hi2 * 256) =
          *(bf16x8*)&Cs[rr * 136 + hh * 64 + j * 8];
    }
  }
}

// ------------- fused flash attention, v7 (r9 form): fragment-major K/V -----
// 512 blocks x 4 waves, 64q/wave, kk-quarters, XCD-pinned 512MB L2 stream,
// ZERO LDS in the loop; register double-buffer one iteration ahead; P stays
// in registers via cvt_pk_bf16 + permlane32_swap. Epilogue LDS 34.8KB.
__global__ __launch_bounds__(256, 2) void attn_kernel(
    const bf16* __restrict__ qp, const bf16* __restrict__ kfg,
    const bf16* __restrict__ vfg, bf16* __restrict__ ctx) {
  const int tid = threadIdx.x;
  const int lane = tid & 63, wave = tid >> 6;  // wave = kk-quarter
  const int l31 = lane & 31, hi = lane >> 5;
  const int hw = blockIdx.x;
  // 512 blocks = 8 XCD x 64; XCD x hosts bh {2x, 2x+1}
  const int xcd = hw & 7, ii = hw >> 3;
  const int bh = xcd * 2 + (ii >> 5), qt = ii & 31;
  const int b = bh >> 3, h = bh & 7;
  const int q0 = qt * 64;

  // LDS: epilogue only. F[4][64][33] f32 (33792B) + Lr[4][64] f32 (1024B)
  __shared__ __align__(16) char smem[34816];

  // Q B-frags (Q^T cols): qf[t][st]: col q = q0+32t+l31, k=d = st*16+hi*8+j
  bf16x8 qf[2][4];
  for (int t = 0; t < 2; ++t)
    for (int st = 0; st < 4; ++st)
      qf[t][st] = ld8(qp + (size_t)(b * LQ + q0 + 32 * t + l31) * E + h * DH +
                      st * 16 + hi * 8);

  float lp[2] = {0.f, 0.f};   // per-lane row-sum partials (q = q0+32t+l31)
  f32x16 acc[2][2] = {};      // [qtile][dtile]; row=q(map), col=d=l31+32dt

  // per-lane fragment bases; tile index t32 = bh*128 + wave*32 + it
  const size_t tb = ((size_t)bh * 128 + wave * 32) * 2048;
  const bf16* kb = kfg + tb + hi * 256 + l31 * 8;
  const bf16* vb = vfg + tb + hi * 256 + l31 * 8;

  // kf_[st]: K[kk=tile*32+l31][d = st*16+hi*8+e]
  // vf_[dt*2+s]: V^T[d=dt*32+l31][kk = tile*32+s*16+hi*8+e]
#define LOADT(kf_, vf_, it)                                          \
  {                                                                  \
    const bf16* kp_ = kb + (size_t)(it) * 2048;                      \
    kf_[0] = ld8(kp_);                                               \
    kf_[1] = ld8(kp_ + 512);                                         \
    kf_[2] = ld8(kp_ + 1024);                                        \
    kf_[3] = ld8(kp_ + 1536);                                        \
    const bf16* vp_ = vb + (size_t)(it) * 2048;                      \
    vf_[0] = ld8(vp_);                                               \
    vf_[1] = ld8(vp_ + 512);                                         \
    vf_[2] = ld8(vp_ + 1024);                                        \
    vf_[3] = ld8(vp_ + 1536);                                        \
  }

  // one 32kk x 64q step on fragment buffers (all-register)
#define COMPUTE(kf_, vf_)                                            \
  _Pragma("unroll")                                                  \
  for (int t = 0; t < 2; ++t) {                                      \
    f32x16 s_ = {};                                                  \
    __builtin_amdgcn_s_setprio(1);                                   \
    s_ = MFMA32(kf_[0], qf[t][0], s_);                               \
    s_ = MFMA32(kf_[1], qf[t][1], s_);                               \
    s_ = MFMA32(kf_[2], qf[t][2], s_);                               \
    s_ = MFMA32(kf_[3], qf[t][3], s_);                               \
    __builtin_amdgcn_s_setprio(0);                                   \
    unsigned w_[4][2];                                               \
    _Pragma("unroll")                                                \
    for (int t4 = 0; t4 < 4; ++t4)                                   \
      _Pragma("unroll")                                              \
      for (int u = 0; u < 2; ++u) {                                  \
        float e0 = EXP2(s_[4 * t4 + 2 * u]);                         \
        float e1 = EXP2(s_[4 * t4 + 2 * u + 1]);                     \
        lp[t] += e0;                                                 \
        lp[t] += e1;                                                 \
        asm("v_cvt_pk_bf16_f32 %0, %1, %2"                           \
            : "=v"(w_[t4][u])                                        \
            : "v"(e0), "v"(e1));                                     \
      }                                                              \
    bf16x8 paf[2];                                                   \
    _Pragma("unroll")                                                \
    for (int s = 0; s < 2; ++s) {                                    \
      unsigned a0 = w_[2 * s][0], b0 = w_[2 * s + 1][0];             \
      unsigned a1 = w_[2 * s][1], b1 = w_[2 * s + 1][1];             \
      asm("v_permlane32_swap_b32 %0, %1" : "+v"(a0), "+v"(b0));      \
      asm("v_permlane32_swap_b32 %0, %1" : "+v"(a1), "+v"(b1));      \
      u32x4 pw_ = {a0, a1, b0, b1};                                  \
      paf[s] = *(bf16x8*)&pw_;                                       \
    }                                                                \
    __builtin_amdgcn_s_setprio(1);                                   \
    acc[t][0] = MFMA32(paf[0], vf_[0], acc[t][0]);                   \
    acc[t][0] = MFMA32(paf[1], vf_[1], acc[t][0]);                   \
    acc[t][1] = MFMA32(paf[0], vf_[2], acc[t][1]);                   \
    acc[t][1] = MFMA32(paf[1], vf_[3], acc[t][1]);                   \
    __builtin_amdgcn_s_setprio(0);                                   \
  }

  bf16x8 kfA[4], vfA[4], kfB[4], vfB[4];
  LOADT(kfA, vfA, 0);
  for (int it = 0; it < 32; it += 2) {
    LOADT(kfB, vfB, it + 1);   // next tile in flight over COMPUTE(A)
    COMPUTE(kfA, vfA);
    if (it + 2 < 32) LOADT(kfA, vfA, it + 2);
    COMPUTE(kfB, vfB);
  }
#undef LOADT
#undef COMPUTE

  // merge lane-halves of row sums: both halves hold full quarter-sum after
  for (int t = 0; t < 2; ++t) lp[t] += __shfl_xor(lp[t], 32);

  float* F = (float*)smem;             // [4][64][33]
  float* Lr = (float*)(smem + 33792);  // [4][64]
  if (hi == 0) {
    Lr[wave * 64 + l31] = lp[0];
    Lr[wave * 64 + 32 + l31] = lp[1];
  }
  // ---- phase dt=0: publish cols 0..31, merge, store ----
#pragma unroll
  for (int t = 0; t < 2; ++t)
#pragma unroll
    for (int r = 0; r < 16; ++r) {
      int q = 32 * t + (r & 3) + 8 * (r >> 2) + 4 * hi;
      F[(wave * 64 + q) * 33 + l31] = acc[t][0][r];
    }
  __syncthreads();
  const int mq = tid >> 2, d0 = (tid & 3) * 8;
  float ls = Lr[mq] + Lr[64 + mq] + Lr[128 + mq] + Lr[192 + mq];
  const float inv = 1.f / ls;
  {
    float o[8] = {};
#pragma unroll
    for (int w2 = 0; w2 < 4; ++w2) {
      const float* Fr = &F[(w2 * 64 + mq) * 33 + d0];
      for (int j = 0; j < 8; ++j) o[j] += Fr[j];
    }
    bf16x8 ov;
    for (int j = 0; j < 8; ++j) ov[j] = (bf16)(o[j] * inv);
    *(bf16x8*)(ctx + (size_t)(b * LQ + q0 + mq) * E + h * DH + d0) = ov;
  }
  __syncthreads();
  // ---- phase dt=1: publish cols 32..63, merge, store ----
#pragma unroll
  for (int t = 0; t < 2; ++t)
#pragma unroll
    for (int r = 0; r < 16; ++r) {
      int q = 32 * t + (r & 3) + 8 * (r >> 2) + 4 * hi;
      F[(wave * 64 + q) * 33 + l31] = acc[t][1][r];
    }
  __syncthreads();
  {
    float o[8] = {};
#pragma unroll
    for (int w2 = 0; w2 < 4; ++w2) {
      const float* Fr = &F[(w2 * 64 + mq) * 33 + d0];
      for (int j = 0; j < 8; ++j) o[j] += Fr[j];
    }
    bf16x8 ov;
    for (int j = 0; j < 8; ++j) ov[j] = (bf16)(o[j] * inv);
    *(bf16x8*)(ctx + (size_t)(b * LQ + q0 + mq) * E + h * DH + 32 + d0) = ov;
  }
}

// ------------- out-projection GEMM: y = ctx @ Wo^T (f32 out) ---------------
// 64x128 tiles (grid 256 blocks), A-only LDS (18KB), B-frags direct from
// frag-major Wo. r12 BUG FIX: A-staging now covers all 64 cols (2 x bf16x8
// per thread: 64 rows x 4 x 16-col chunks = full 64x64 tile).
__global__ __launch_bounds__(256) void outgemm_kernel(
    const bf16* __restrict__ Cx, const bf16* __restrict__ Wof,
    float* __restrict__ y) {
  __shared__ bf16 smA[2][64][72];
  const int tid = threadIdx.x;
  const int lane = tid & 63, wave = tid >> 6;
  const int lrow = lane & 15, quad = lane >> 4;
  const int wm = wave & 1, wn = wave >> 1;
  const int m0 = blockIdx.x * 64, n0 = blockIdx.y * 128;
  const bf16* A = Cx + (size_t)m0 * E;

  const int srow = tid >> 2, sc0 = (tid & 3) * 16;  // 64 rows x 4 x 16 cols
  const bf16* wb = Wof + (size_t)lane * 8;
  const int n16b = (n0 >> 4) + wn * 4;

  bf16x8 pa1, pa2;
  bf16x8 bfr[2][4];
#define LOAD_A(t)                                                             \
  {                                                                           \
    const bf16* ap_ = A + (size_t)srow * E + (t) * 64 + sc0;                  \
    pa1 = ld8(ap_);                                                           \
    pa2 = ld8(ap_ + 8);                                                       \
  }
#define STORE_A(bs)                                                           \
  {                                                                           \
    *(bf16x8*)&smA[bs][srow][sc0] = pa1;                                      \
    *(bf16x8*)&smA[bs][srow][sc0 + 8] = pa2;                                  \
  }
#define LOAD_B(t)                                                             \
  for (int ks = 0; ks < 2; ++ks)                                              \
    for (int c = 0; c < 4; ++c)                                               \
      bfr[ks][c] =                                                            \
          ld8(wb + (size_t)((n16b + c) * 16 + 2 * (t) + ks) * 512);

  LOAD_A(0);
  STORE_A(0);
  LOAD_A(1);
  LOAD_B(0);
  __syncthreads();

  f32x4 acc[2][4] = {};
  for (int t = 0; t < 8; ++t) {
    const int bs = t & 1;
    bf16x8 af[2][2];
    for (int ks = 0; ks < 2; ++ks)
      for (int i = 0; i < 2; ++i)
        af[ks][i] = ld8(&smA[bs][wm * 32 + 16 * i + lrow][ks * 32 + quad * 8]);
    for (int ks = 0; ks < 2; ++ks)
      for (int i = 0; i < 2; ++i)
        for (int c = 0; c < 4; ++c)
          acc[i][c] = MFMA16(af[ks][i], bfr[ks][c], acc[i][c]);
    if (t < 7) {
      LOAD_B(t + 1);
      STORE_A(bs ^ 1);
      if (t < 6) LOAD_A(t + 2);
    }
    __syncthreads();
  }
#undef LOAD_A
#undef STORE_A
#undef LOAD_B

  for (int i = 0; i < 2; ++i)
    for (int c = 0; c < 4; ++c)
      for (int r = 0; r < 4; ++r) {
        int row = m0 + wm * 32 + 16 * i + 4 * quad + r;
        int col = n0 + wn * 64 + 16 * c + lrow;
        y[(size_t)row * E + col] = acc[i][c][r];
      }
}

// ------------- bias + residual + LayerNorm (memory-bound) ------------------
__global__ __launch_bounds__(256) void ln_kernel(
    const float* __restrict__ y, const float* __restrict__ resid,
    const float* __restrict__ bo, const float* __restrict__ gamma,
    const float* __restrict__ beta, float* __restrict__ out) {
  const int tid = threadIdx.x;
  const int lane = tid & 63, wave = tid >> 6;
  const int row = blockIdx.x * 4 + wave;
  const int c0 = lane * 8;

  const float* yr = y + (size_t)row * E + c0;
  const float* rr = resid + (size_t)row * E + c0;
  f32x4 y0 = *(const f32x4*)yr, y1 = *(const f32x4*)(yr + 4);
  f32x4 r0 = *(const f32x4*)rr, r1 = *(const f32x4*)(rr + 4);
  f32x4 b0 = *(const f32x4*)(bo + c0), b1 = *(const f32x4*)(bo + c0 + 4);

  float xv[8];
  float s1 = 0.f, s2 = 0.f;
  for (int j = 0; j < 4; ++j) {
    xv[j] = y0[j] + r0[j] + b0[j];
    xv[4 + j] = y1[j] + r1[j] + b1[j];
  }
  for (int j = 0; j < 8; ++j) {
    s1 += xv[j];
    s2 += xv[j] * xv[j];
  }
  for (int off = 1; off < 64; off <<= 1) {
    s1 += __shfl_xor(s1, off);
    s2 += __shfl_xor(s2, off);
  }
  const float mean = s1 * (1.f / 512.f);
  const float var = s2 * (1.f / 512.f) - mean * mean;
  const float rstd = rsqrtf(var + 1e-5f);

  f32x4 g0 = *(const f32x4*)(gamma + c0), g1 = *(const f32x4*)(gamma + c0 + 4);
  f32x4 t0 = *(const f32x4*)(beta + c0), t1 = *(const f32x4*)(beta + c0 + 4);
  f32x4 o0, o1;
  for (int j = 0; j < 4; ++j) {
    o0[j] = (xv[j] - mean) * rstd * g0[j] + t0[j];
    o1[j] = (xv[4 + j] - mean) * rstd * g1[j] + t1[j];
  }
  float* op = out + (size_t)row * E + c0;
  *(f32x4*)op = o0;
  *(f32x4*)(op + 4) = o1;
}

extern "C" void kernel_launch(void* const* d_in, const int* in_sizes, int n_in,
                              void* d_out, int out_size, void* d_ws, size_t ws_size,
                              hipStream_t stream) {
  const float* query     = (const float*)d_in[0];
  const float* key_value = (const float*)d_in[1];
  const float* Wq = (const float*)d_in[2];
  const float* bq = (const float*)d_in[3];
  const float* Wk = (const float*)d_in[4];
  const float* bk = (const float*)d_in[5];
  const float* Wv = (const float*)d_in[6];
  const float* bv = (const float*)d_in[7];
  const float* Wo = (const float*)d_in[8];
  const float* bo = (const float*)d_in[9];
  const float* gamma = (const float*)d_in[10];
  const float* beta  = (const float*)d_in[11];
  float* out = (float*)d_out;

  // ws layout: 4 weights (frag-major bf16) | qproj(=ctx) | kproj(frag) |
  //            vt(frag) | y f32
  bf16* Wb    = (bf16*)d_ws;
  bf16* Wob   = Wb + (size_t)3 * 262144;
  bf16* qproj = Wb + (size_t)4 * 262144;
  bf16* kproj = qproj + (size_t)4096 * 512;
  bf16* vt    = kproj + (size_t)8192 * 512;
  float* y    = (float*)(vt + (size_t)8192 * 512);

  cvt4f_kernel<<<512, 256, 0, stream>>>(Wq, Wk, Wv, Wo, Wb);
  proj_gemm_kernel<<<dim3(160, 4), 256, 0, stream>>>(
      query, key_value, Wb, bq, bk, bv, qproj, kproj, vt);
  attn_kernel<<<512, 256, 0, stream>>>(qproj, kproj, vt, qproj /*ctx in-place*/);
  outgemm_kernel<<<dim3(64, 4), 256, 0, stream>>>(qproj, Wob, y);
  ln_kernel<<<1024, 256, 0, stream>>>(y, query, bo, gamma, beta, out);
}